// Round 4
// baseline (173.925 us; speedup 1.0000x reference)
//
#include <hip/hip_runtime.h>

#define L_TOT 10752
#define NF    256
#define BATCHN 4096

typedef __attribute__((ext_vector_type(8))) short short8;   // 8 bf16
typedef __attribute__((ext_vector_type(4))) float f32x4;

__device__ __forceinline__ unsigned short f2bf(float f) {
  unsigned int u = __float_as_uint(f);
  unsigned int r = (u + 0x7FFFu + ((u >> 16) & 1u)) >> 16;  // RNE
  return (unsigned short)r;
}

__device__ __forceinline__ float tanh_fast(float x) {
  float e2 = __builtin_amdgcn_exp2f(x * 2.8853900817779268f); // 2*log2(e)
  float r  = __builtin_amdgcn_rcpf(e2 + 1.0f);
  return fmaf(-2.0f, r, 1.0f);
}

// ---------------- schedules (reduction masks; layout verified in R2) ----------
// Row layout per formula (n3 = NC/3): d6 rows [0,8n3) (8 rows/conj: 6 real+2 pad,
// quad-pair q<->q^1), d4 rows [8n3,12n3), d2 rows [12n3,14n3), tail pad to NT*16.
template<int G> struct Sch;
template<> struct Sch<0> {  // NC=6, n3=2
  static constexpr int NT = 2, NC = 6;
  static constexpr int p6[2]  = {0b11, 0};
  static constexpr int m4[2]  = {0, 0b0011};
  static constexpr int m2a[2] = {0, 0b0100};
  static constexpr int m2b[2] = {0, 0b0100};
};
template<> struct Sch<1> {  // NC=9, n3=3
  static constexpr int NT = 3, NC = 9;
  static constexpr int p6[3]  = {0b11, 0b01, 0};
  static constexpr int m4[3]  = {0, 0b1100, 0b0001};
  static constexpr int m2a[3] = {0, 0, 0b0110};
  static constexpr int m2b[3] = {0, 0, 0b0010};
};
template<> struct Sch<2> {  // NC=12, n3=4
  static constexpr int NT = 4, NC = 12;
  static constexpr int p6[4]  = {0b11, 0b11, 0, 0};
  static constexpr int m4[4]  = {0, 0, 0b1111, 0};
  static constexpr int m2a[4] = {0, 0, 0, 0b0011};
  static constexpr int m2b[4] = {0, 0, 0, 0b0011};
};
template<> struct Sch<3> {  // NC=15, n3=5
  static constexpr int NT = 5, NC = 15;
  static constexpr int p6[5]  = {0b11, 0b11, 0b01, 0, 0};
  static constexpr int m4[5]  = {0, 0, 0b1100, 0b0111, 0};
  static constexpr int m2a[5] = {0, 0, 0, 0b1000, 0b0011};
  static constexpr int m2b[5] = {0, 0, 0, 0b1000, 0b0001};
};

// ---------------- prep: A2 (x^2|x bf16) + B2/cf ------------------------------
__global__ __launch_bounds__(256) void prep_xb(
    const float4* __restrict__ x4, ushort4* __restrict__ a2,
    const float* __restrict__ mu, const float* __restrict__ sigma,
    unsigned short* __restrict__ B2, float* __restrict__ cf)
{
  int bi = blockIdx.x, tid = threadIdx.x;
  if (bi < 512) {                       // ---- prep_x
    int i = bi * 256 + tid;             // 4096*32
    float4 v = x4[i];
    int b = i >> 5, kc = i & 31;
    ushort4 sq, xx;
    sq.x = f2bf(v.x * v.x); sq.y = f2bf(v.y * v.y);
    sq.z = f2bf(v.z * v.z); sq.w = f2bf(v.w * v.w);
    xx.x = f2bf(v.x); xx.y = f2bf(v.y); xx.z = f2bf(v.z); xx.w = f2bf(v.w);
    a2[b * 64 + kc] = sq;
    a2[b * 64 + 32 + kc] = xx;
  } else {                              // ---- prep_b (4 formulas/block, 1/wave)
    int f = (bi - 512) * 4 + (tid >> 6);
    int k = tid & 63;
    float acc = 0.0f;
    for (int kk = k; kk < 128; kk += 64) {
      float s = sigma[f * 128 + kk], m = mu[f * 128 + kk];
      float s2 = s * s;
      B2[f * 256 + kk] = f2bf(s2);
      B2[f * 256 + 128 + kk] = f2bf(-2.0f * m * s2);
      acc = fmaf(m * m, s2, acc);
    }
    for (int o = 1; o < 64; o <<= 1) acc += __shfl_xor(acc, o);
    if (k == 0) cf[f] = acc;
  }
}

// ---------------- main: in-block W transpose + dual-acc pipelined GEMM --------
__device__ __forceinline__ short8 ldsw(const unsigned short* s_w, int row, int colb) {
  // XOR swizzle: row stride 256B would put all 16 n-lanes in one bank cluster
  int off = (row << 8) + (colb ^ ((row & 7) << 4));
  return *reinterpret_cast<const short8*>(reinterpret_cast<const char*>(s_w) + off);
}

template<int G>
__device__ __forceinline__ void mfma_tile(const unsigned short* s_w,
                                          const short8* xc, f32x4* ac,
                                          int n, int q)
{
  constexpr int NT = Sch<G>::NT;
#pragma unroll
  for (int t = 0; t < NT; ++t) ac[t] = (f32x4){0.f, 0.f, 0.f, 0.f};
#pragma unroll
  for (int kk = 0; kk < 4; ++kk)
#pragma unroll
    for (int t = 0; t < NT; ++t)
      ac[t] = __builtin_amdgcn_mfma_f32_16x16x32_bf16(
          ldsw(s_w, t * 16 + n, kk * 64 + q * 16), xc[kk], ac[t], 0, 0, 0);
}

template<int G>
__device__ __forceinline__ void reduce_store(const f32x4* ac, const float* s_bias,
                                             float* __restrict__ dnnf,
                                             int f, int brow, int n, int q, int lane)
{
  using S = Sch<G>;
  float fs = 0.0f;
#pragma unroll
  for (int t = 0; t < S::NT; ++t) {
    f32x4 brg = *reinterpret_cast<const f32x4*>(&s_bias[t * 16 + q * 4]);
    float v0 = tanh_fast(ac[t][0] + brg[0]);
    float v1 = tanh_fast(ac[t][1] + brg[1]);
    float v2 = tanh_fast(ac[t][2] + brg[2]);
    float v3 = tanh_fast(ac[t][3] + brg[3]);
    float s = v0 + v1 + v2 + v3;
    if (S::p6[t]) {                       // depth-6: quad-pair q <-> q^1
      float po = __shfl_xor(s, 16);
      float t6 = tanh_fast(s + po - 4.5f);
      bool add = ((q & 1) == 0) && ((S::p6[t] >> (q >> 1)) & 1);
      fs += add ? t6 : 0.0f;
    }
    if (S::m4[t]) {                       // depth-4: whole quad
      float t4 = tanh_fast(s - 2.5f);
      fs += ((S::m4[t] >> q) & 1) ? t4 : 0.0f;
    }
    if (S::m2a[t]) {                      // depth-2: rows 0,1
      float ta = tanh_fast(v0 + v1 - 0.5f);
      fs += ((S::m2a[t] >> q) & 1) ? ta : 0.0f;
    }
    if (S::m2b[t]) {                      // depth-2: rows 2,3
      float tb = tanh_fast(v2 + v3 - 0.5f);
      fs += ((S::m2b[t] >> q) & 1) ? tb : 0.0f;
    }
  }
  fs += __shfl_xor(fs, 16);
  fs += __shfl_xor(fs, 32);
  float dv = tanh_fast(fs + (float)S::NC - 1.5f);
  if (lane < 16)
    dnnf[(size_t)f * BATCHN + brow + n] = dv;   // coalesced 64B
}

template<int G>
__device__ __forceinline__ void dnnf_body(
    const unsigned short* __restrict__ A2,   // [4096][256] bf16 (x at +128)
    const float* __restrict__ weight,
    const float* __restrict__ bias,
    const float* __restrict__ lm,
    float* __restrict__ dnnf,                // [256][4096]
    int f, int ls, int batch0,
    unsigned short* s_w, float* s_bias)
{
  using S = Sch<G>;
  constexpr int NT = S::NT;
  constexpr int n3 = S::NC / 3;
  constexpr int LF = 12 * n3;
  const int tid = threadIdx.x;
  const int lane = tid & 63;
  const int wv = tid >> 6;
  const int n = lane & 15;
  const int q = lane >> 4;

  // ---- zero tile (pad rows must be 0), then masked transpose weight -> LDS --
  {
    unsigned long long* p = reinterpret_cast<unsigned long long*>(s_w);
    constexpr int n64 = NT * 512;         // 8B words in NT*16 rows
#pragma unroll
    for (int i = tid; i < n64; i += 256) p[i] = 0ull;
    if (tid < NT * 16) s_bias[tid] = 0.0f;
  }
  __syncthreads();
  for (int e = tid; e < 128 * LF; e += 256) {
    int k = e / LF;                       // const divisor -> magic mul
    int j = e - k * LF;
    float m = (fabsf(lm[k * NF + f]) > 1.0f) ? 1.0f : 0.0f;
    unsigned short w = f2bf(weight[(size_t)k * L_TOT + ls + j] * m);
    int R;                                // inverse of the padded-row layout
    if (j < 2 * n3)      R = j + 12 * n3;               // depth-2 lits
    else if (j < 6 * n3) R = j + 6 * n3;                // depth-4 lits
    else { unsigned u = (unsigned)(j - 6 * n3); unsigned c = u / 6u;
           R = 8 * (int)c + (int)(u - 6u * c); }        // depth-6 lits
    s_w[(R << 7) + (k ^ ((R & 7) << 3))] = w;           // swizzled 2B store
    if (e < LF) s_bias[R] = bias[ls + j];               // k==0 threads
  }
  __syncthreads();

  // ---- 8 batch iters, dual-accumulator pipeline: MFMA(i+1) || reduce(i) -----
  const unsigned short* xr0 = A2 + (size_t)(batch0 + wv * 16 + n) * 256 + 128;
  short8 xb[2][4];
  f32x4 ac[2][NT];
#pragma unroll
  for (int kk = 0; kk < 4; ++kk)
    xb[0][kk] = *reinterpret_cast<const short8*>(xr0 + kk * 32 + q * 8);
  mfma_tile<G>(s_w, xb[0], ac[0], n, q);
#pragma unroll
  for (int kk = 0; kk < 4; ++kk)
    xb[1][kk] = *reinterpret_cast<const short8*>(xr0 + 64 * 256 + kk * 32 + q * 8);

#pragma unroll
  for (int i = 0; i < 8; ++i) {
    const int cur = i & 1, nxt = cur ^ 1;
    if (i + 2 < 8) {                      // loads for iter i+2 (xb[cur] free)
      const unsigned short* xr = xr0 + (size_t)(i + 2) * 64 * 256;
#pragma unroll
      for (int kk = 0; kk < 4; ++kk)
        xb[cur][kk] = *reinterpret_cast<const short8*>(xr + kk * 32 + q * 8);
    }
    if (i + 1 < 8)                        // matrix pipe: iter i+1
      mfma_tile<G>(s_w, xb[nxt], ac[nxt], n, q);
    // VALU/trans: reduce iter i (overlaps the MFMAs above)
    reduce_store<G>(ac[cur], s_bias, dnnf, f, batch0 + i * 64 + wv * 16, n, q, lane);
  }
}

__global__ __launch_bounds__(256, 2) void dnnf_main(
    const unsigned short* __restrict__ A2,
    const float* __restrict__ weight,
    const float* __restrict__ bias,
    const float* __restrict__ lm,
    float* __restrict__ dnnf)
{
  __shared__ __align__(16) unsigned short s_w[80 * 128];   // 20 KB max tile
  __shared__ __align__(16) float s_bias[80];
  int bi = blockIdx.x;
  int u = bi >> 3;                        // formula slot 0..255
  int f = ((u & 3) << 6) | (u >> 2);      // interleave G0..G3 for load balance
  int batch0 = (bi & 7) * 512;
  int g = u & 3, fo = u >> 2;
  if (g == 0)      dnnf_body<0>(A2, weight, bias, lm, dnnf, f, 0    + fo * 24, batch0, s_w, s_bias);
  else if (g == 1) dnnf_body<1>(A2, weight, bias, lm, dnnf, f, 1536 + fo * 36, batch0, s_w, s_bias);
  else if (g == 2) dnnf_body<2>(A2, weight, bias, lm, dnnf, f, 3840 + fo * 48, batch0, s_w, s_bias);
  else             dnnf_body<3>(A2, weight, bias, lm, dnnf, f, 6912 + fo * 60, batch0, s_w, s_bias);
}

// ---------------- loc GEMM + softmax + multiply (16 waves/block) --------------
__global__ __launch_bounds__(1024) void loc_fused(
    const unsigned short* __restrict__ A2,   // [4096][256] bf16
    const unsigned short* __restrict__ B2,   // [256][256] bf16
    const float* __restrict__ cf,            // [256]
    const float* __restrict__ temp,
    const float* __restrict__ dnnf,          // [256][4096]
    float* __restrict__ out)                 // [4096][256]
{
  __shared__ float s_part[16][16];
  int tid = threadIdx.x, lane = tid & 63, w = tid >> 6, n = lane & 15, q = lane >> 4;
  int b0 = blockIdx.x * 16;

  const unsigned short* arow = A2 + (size_t)(b0 + n) * 256;
  const unsigned short* brow = B2 + (size_t)(w * 16 + n) * 256;
  f32x4 acc = (f32x4){0.f, 0.f, 0.f, 0.f};
#pragma unroll
  for (int kk = 0; kk < 8; ++kk) {
    short8 af = *reinterpret_cast<const short8*>(arow + kk * 32 + q * 8);
    short8 bf = *reinterpret_cast<const short8*>(brow + kk * 32 + q * 8);
    acc = __builtin_amdgcn_mfma_f32_16x16x32_bf16(af, bf, acc, 0, 0, 0);
  }

  float T = temp[0];
  float sg = 1.0f / (1.0f + __builtin_amdgcn_exp2f(-T * 1.4426950408889634f));
  float ez[4];
  float sr[4];
  float c = cf[w * 16 + n];
#pragma unroll
  for (int r = 0; r < 4; ++r) {
    float n2 = fmaxf(acc[r] + c, 0.0f);
    float loc = __builtin_amdgcn_exp2f(-__builtin_amdgcn_sqrtf(n2) * 1.4426950408889634f);
    float e = __builtin_amdgcn_exp2f(sg * loc * 1.4426950408889634f);
    ez[r] = e;
    sr[r] = e;
  }
#pragma unroll
  for (int o = 1; o < 16; o <<= 1)
#pragma unroll
    for (int r = 0; r < 4; ++r) sr[r] += __shfl_xor(sr[r], o);
  if (n == 0) {
#pragma unroll
    for (int r = 0; r < 4; ++r) s_part[w][q * 4 + r] = sr[r];
  }
  __syncthreads();
  float rtot[4];
#pragma unroll
  for (int r = 0; r < 4; ++r) {
    float tot = 0.0f;
#pragma unroll
    for (int ww = 0; ww < 16; ++ww) tot += s_part[ww][q * 4 + r];
    rtot[r] = 1.0f / tot;
  }
#pragma unroll
  for (int r = 0; r < 4; ++r) {
    int fc = w * 16 + n;
    int bg = b0 + q * 4 + r;
    out[(size_t)bg * 256 + fc] = dnnf[(size_t)fc * BATCHN + bg] * ez[r] * rtot[r];
  }
}

extern "C" void kernel_launch(void* const* d_in, const int* in_sizes, int n_in,
                              void* d_out, int out_size, void* d_ws, size_t ws_size,
                              hipStream_t stream) {
  const float* x      = (const float*)d_in[0];
  const float* weight = (const float*)d_in[1];
  const float* bias   = (const float*)d_in[2];
  const float* lm     = (const float*)d_in[3];
  const float* mu     = (const float*)d_in[4];
  const float* sigma  = (const float*)d_in[5];
  const float* temp   = (const float*)d_in[6];
  float* out = (float*)d_out;

  char* ws = (char*)d_ws;
  unsigned short* A2     = (unsigned short*)(ws);                 // 2 MB
  float*          dnnf   = (float*)(ws + 2097152);                // 4 MB [f][b]
  unsigned short* B2     = (unsigned short*)(ws + 6291456);       // 128 KB
  float*          cf     = (float*)(ws + 6422528);                // 1 KB

  prep_xb<<<576, 256, 0, stream>>>((const float4*)x, (ushort4*)A2,
                                   mu, sigma, B2, cf);
  dnnf_main<<<2048, 256, 0, stream>>>(A2, weight, bias, lm, dnnf);
  loc_fused<<<256, 1024, 0, stream>>>(A2, B2, cf, temp, dnnf, out);
}